// Round 3
// baseline (66.538 us; speedup 1.0000x reference)
//
#include <hip/hip_runtime.h>

#define B_ROWS 2048
#define C_TOTAL 1000
#define C_LOADED 256
#define NEG_PEN 0.03f
#define NV4 250          // 1000 / 4

// ws layout: [0:4) float total, [4:8) int n_valid, [16:16+4000) int cnt[1000]

__global__ void count_kernel(const int* __restrict__ ids, int* __restrict__ cnt) {
    atomicAdd(&cnt[ids[threadIdx.x]], 1);
}

__global__ void __launch_bounds__(256)
rank_loss_kernel(const float* __restrict__ ranks,
                 const int* __restrict__ labels,
                 const int* __restrict__ cnt,
                 float* __restrict__ ws_total,
                 int* __restrict__ ws_nvalid) {
    __shared__ __align__(16) float negl[264];   // r_neg + pen, duplicate-expanded
    __shared__ float posl[256];                 // r_pos, duplicate-expanded
    __shared__ int packed_counter;              // npos<<16 | nneg
    __shared__ float wave_sums[4];

    const int b = blockIdx.x;
    const int t = threadIdx.x;
    const int lane = t & 63;
    const int wave = t >> 6;

    if (t == 0) packed_counter = 0;

    // fully coalesced row loads (row base b*4000B is 16B-aligned)
    float4 rv = {0.f, 0.f, 0.f, 0.f};
    int4 lv = {0, 0, 0, 0};
    int4 cv = {0, 0, 0, 0};
    if (t < NV4) {
        rv = ((const float4*)(ranks + (size_t)b * C_TOTAL))[t];
        lv = ((const int4*)(labels + (size_t)b * C_TOTAL))[t];
        cv = ((const int4*)cnt)[t];
    }
    const float rs[4] = {rv.x, rv.y, rv.z, rv.w};
    const int labs[4] = {lv.x, lv.y, lv.z, lv.w};
    const int cs[4]   = {cv.x, cv.y, cv.z, cv.w};

    // packed per-thread slot counts (npos<<16 | nneg); totals <= 256 each
    int np = 0, nn = 0;
#pragma unroll
    for (int k = 0; k < 4; ++k) {
        np += (labs[k] == 1) ? cs[k] : 0;
        nn += (labs[k] == 0) ? cs[k] : 0;
    }
    const int mine = (np << 16) | nn;

    // wave inclusive prefix sum
    int incl = mine;
#pragma unroll
    for (int off = 1; off < 64; off <<= 1) {
        int y = __shfl_up(incl, off, 64);
        if (lane >= off) incl += y;
    }
    const int wtotal = __shfl(incl, 63, 64);
    const int excl = incl - mine;

    __syncthreads();              // packed_counter zeroed before atomics

    int wbase = 0;
    if (lane == 63) wbase = atomicAdd(&packed_counter, wtotal);
    wbase = __shfl(wbase, 63, 64);
    int pbase = ((wbase + excl) >> 16) & 0xffff;
    int nbase = (wbase + excl) & 0xffff;

    // compaction with duplicate expansion
#pragma unroll
    for (int k = 0; k < 4; ++k) {
        const int c = cs[k];
        if (labs[k] == 1) {
            for (int d = 0; d < c; ++d) posl[pbase++] = rs[k];
        } else {
            for (int d = 0; d < c; ++d) negl[nbase++] = rs[k] + NEG_PEN;
        }
    }
    __syncthreads();

    const int tot  = packed_counter;
    const int npos = (tot >> 16) & 0xffff;
    const int nneg = tot & 0xffff;
    const int npad = (nneg + 7) & ~7;
    if (t >= nneg && t < npad) negl[t] = -1e30f;   // pad -> relu==0
    __syncthreads();

    float acc = 0.f;
    if (t < npos) {
        const float rp = posl[t];
        float a0 = 0.f, a1 = 0.f, a2 = 0.f, a3 = 0.f;
        float a4 = 0.f, a5 = 0.f, a6 = 0.f, a7 = 0.f;
        const float4* n4 = (const float4*)negl;
        const int G = npad >> 2;
        for (int g = 0; g < G; g += 2) {
            float4 x = n4[g];
            float4 y = n4[g + 1];
            a0 += fmaxf(x.x - rp, 0.0f);
            a1 += fmaxf(x.y - rp, 0.0f);
            a2 += fmaxf(x.z - rp, 0.0f);
            a3 += fmaxf(x.w - rp, 0.0f);
            a4 += fmaxf(y.x - rp, 0.0f);
            a5 += fmaxf(y.y - rp, 0.0f);
            a6 += fmaxf(y.z - rp, 0.0f);
            a7 += fmaxf(y.w - rp, 0.0f);
        }
        acc = ((a0 + a1) + (a2 + a3)) + ((a4 + a5) + (a6 + a7));
    }

    // wave reduction
#pragma unroll
    for (int off = 32; off > 0; off >>= 1) {
        acc += __shfl_down(acc, off, 64);
    }
    if (lane == 0) wave_sums[wave] = acc;
    __syncthreads();

    if (t == 0) {
        float s = (wave_sums[0] + wave_sums[1]) + (wave_sums[2] + wave_sums[3]);
        atomicAdd(ws_total, s);
        if (npos > 0) atomicAdd(ws_nvalid, 1);
    }
}

__global__ void finalize_kernel(const float* __restrict__ ws_total,
                                const int* __restrict__ ws_nvalid,
                                float* __restrict__ out) {
    out[0] = ws_total[0] / (float)ws_nvalid[0];
}

extern "C" void kernel_launch(void* const* d_in, const int* in_sizes, int n_in,
                              void* d_out, int out_size, void* d_ws, size_t ws_size,
                              hipStream_t stream) {
    const float* ranks  = (const float*)d_in[0];
    const int*   labels = (const int*)d_in[1];
    const int*   ids    = (const int*)d_in[2];
    float* out = (float*)d_out;

    float* ws_total  = (float*)d_ws;
    int*   ws_nvalid = (int*)((char*)d_ws + 4);
    int*   cnt       = (int*)((char*)d_ws + 16);

    hipMemsetAsync(d_ws, 0, 16 + C_TOTAL * sizeof(int), stream);
    count_kernel<<<1, C_LOADED, 0, stream>>>(ids, cnt);
    rank_loss_kernel<<<B_ROWS, 256, 0, stream>>>(ranks, labels, cnt,
                                                 ws_total, ws_nvalid);
    finalize_kernel<<<1, 1, 0, stream>>>(ws_total, ws_nvalid, out);
}

// Round 4
// 20.372 us; speedup vs baseline: 3.2661x; 3.2661x over previous
//
#include <hip/hip_runtime.h>

#define B_ROWS 2048
#define C_TOTAL 1000
#define C_LOADED 256
#define NEG_PEN 0.03f
#define NV4 250          // 1000 / 4

// ws layout:
//   [0      : 8192)   float part[2048]    per-block partial sums
//   [8192   : 16384)  float validf[2048]  per-block "has positive" flag
//   [16384  : 20384)  int   cnt[1000]     class multiplicity table

__global__ void __launch_bounds__(1024)
count_kernel(const int* __restrict__ ids, int* __restrict__ cnt) {
    const int t = threadIdx.x;
    if (t < C_TOTAL) cnt[t] = 0;
    __syncthreads();
    if (t < C_LOADED) atomicAdd(&cnt[ids[t]], 1);
}

__global__ void __launch_bounds__(256)
rank_loss_kernel(const float* __restrict__ ranks,
                 const int* __restrict__ labels,
                 const int* __restrict__ cnt,
                 float* __restrict__ part,
                 float* __restrict__ validf) {
    __shared__ __align__(16) float negl[264];   // r_neg + pen, duplicate-expanded
    __shared__ float posl[256];                 // r_pos, duplicate-expanded
    __shared__ int packed_counter;              // npos<<16 | nneg
    __shared__ float wave_sums[4];

    const int b = blockIdx.x;
    const int t = threadIdx.x;
    const int lane = t & 63;
    const int wave = t >> 6;

    if (t == 0) packed_counter = 0;

    // fully coalesced row loads (row base b*4000B is 16B-aligned)
    float4 rv = {0.f, 0.f, 0.f, 0.f};
    int4 lv = {0, 0, 0, 0};
    int4 cv = {0, 0, 0, 0};
    if (t < NV4) {
        rv = ((const float4*)(ranks + (size_t)b * C_TOTAL))[t];
        lv = ((const int4*)(labels + (size_t)b * C_TOTAL))[t];
        cv = ((const int4*)cnt)[t];
    }
    const float rs[4] = {rv.x, rv.y, rv.z, rv.w};
    const int labs[4] = {lv.x, lv.y, lv.z, lv.w};
    const int cs[4]   = {cv.x, cv.y, cv.z, cv.w};

    // packed per-thread slot counts (npos<<16 | nneg); totals <= 256 each
    int np = 0, nn = 0;
#pragma unroll
    for (int k = 0; k < 4; ++k) {
        np += (labs[k] == 1) ? cs[k] : 0;
        nn += (labs[k] == 0) ? cs[k] : 0;
    }
    const int mine = (np << 16) | nn;

    // wave inclusive prefix sum
    int incl = mine;
#pragma unroll
    for (int off = 1; off < 64; off <<= 1) {
        int y = __shfl_up(incl, off, 64);
        if (lane >= off) incl += y;
    }
    const int wtotal = __shfl(incl, 63, 64);
    const int excl = incl - mine;

    __syncthreads();              // packed_counter zeroed before atomics

    int wbase = 0;
    if (lane == 63) wbase = atomicAdd(&packed_counter, wtotal);
    wbase = __shfl(wbase, 63, 64);
    int pbase = ((wbase + excl) >> 16) & 0xffff;
    int nbase = (wbase + excl) & 0xffff;

    // compaction with duplicate expansion
#pragma unroll
    for (int k = 0; k < 4; ++k) {
        const int c = cs[k];
        if (labs[k] == 1) {
            for (int d = 0; d < c; ++d) posl[pbase++] = rs[k];
        } else {
            for (int d = 0; d < c; ++d) negl[nbase++] = rs[k] + NEG_PEN;
        }
    }
    __syncthreads();

    const int tot  = packed_counter;
    const int npos = (tot >> 16) & 0xffff;
    const int nneg = tot & 0xffff;
    const int npad = (nneg + 7) & ~7;
    if (t >= nneg && t < npad) negl[t] = -1e30f;   // pad -> relu==0
    __syncthreads();

    float acc = 0.f;
    if (t < npos) {
        const float rp = posl[t];
        float a0 = 0.f, a1 = 0.f, a2 = 0.f, a3 = 0.f;
        float a4 = 0.f, a5 = 0.f, a6 = 0.f, a7 = 0.f;
        const float4* n4 = (const float4*)negl;
        const int G = npad >> 2;
        for (int g = 0; g < G; g += 2) {
            float4 x = n4[g];
            float4 y = n4[g + 1];
            a0 += fmaxf(x.x - rp, 0.0f);
            a1 += fmaxf(x.y - rp, 0.0f);
            a2 += fmaxf(x.z - rp, 0.0f);
            a3 += fmaxf(x.w - rp, 0.0f);
            a4 += fmaxf(y.x - rp, 0.0f);
            a5 += fmaxf(y.y - rp, 0.0f);
            a6 += fmaxf(y.z - rp, 0.0f);
            a7 += fmaxf(y.w - rp, 0.0f);
        }
        acc = ((a0 + a1) + (a2 + a3)) + ((a4 + a5) + (a6 + a7));
    }

    // wave reduction
#pragma unroll
    for (int off = 32; off > 0; off >>= 1) {
        acc += __shfl_down(acc, off, 64);
    }
    if (lane == 0) wave_sums[wave] = acc;
    __syncthreads();

    if (t == 0) {
        part[b]   = (wave_sums[0] + wave_sums[1]) + (wave_sums[2] + wave_sums[3]);
        validf[b] = (npos > 0) ? 1.0f : 0.0f;
    }
}

__global__ void __launch_bounds__(1024)
finalize_kernel(const float* __restrict__ part,
                const float* __restrict__ validf,
                float* __restrict__ out) {
    __shared__ float ws_s[16], ws_v[16];
    const int t = threadIdx.x;
    const int lane = t & 63;
    const int wave = t >> 6;

    float2 p = ((const float2*)part)[t];
    float2 v = ((const float2*)validf)[t];
    float s = p.x + p.y;
    float nv = v.x + v.y;

#pragma unroll
    for (int off = 32; off > 0; off >>= 1) {
        s  += __shfl_down(s, off, 64);
        nv += __shfl_down(nv, off, 64);
    }
    if (lane == 0) { ws_s[wave] = s; ws_v[wave] = nv; }
    __syncthreads();

    if (t == 0) {
        float ts = 0.f, tv = 0.f;
#pragma unroll
        for (int w = 0; w < 16; ++w) { ts += ws_s[w]; tv += ws_v[w]; }
        out[0] = ts / tv;
    }
}

extern "C" void kernel_launch(void* const* d_in, const int* in_sizes, int n_in,
                              void* d_out, int out_size, void* d_ws, size_t ws_size,
                              hipStream_t stream) {
    const float* ranks  = (const float*)d_in[0];
    const int*   labels = (const int*)d_in[1];
    const int*   ids    = (const int*)d_in[2];
    float* out = (float*)d_out;

    float* part   = (float*)d_ws;
    float* validf = (float*)((char*)d_ws + 8192);
    int*   cnt    = (int*)((char*)d_ws + 16384);

    count_kernel<<<1, 1024, 0, stream>>>(ids, cnt);
    rank_loss_kernel<<<B_ROWS, 256, 0, stream>>>(ranks, labels, cnt, part, validf);
    finalize_kernel<<<1, 1024, 0, stream>>>(part, validf, out);
}

// Round 5
// 13.652 us; speedup vs baseline: 4.8738x; 1.4922x over previous
//
#include <hip/hip_runtime.h>

#define B_ROWS 2048
#define C_TOTAL 1000
#define C_LOADED 256
#define NEG_PEN 0.03f

// ws layout: [0 : 16384) float2 pv[2048] — {partial_sum, valid_flag} per block

__global__ void __launch_bounds__(C_LOADED)
rank_loss_kernel(const float* __restrict__ ranks,
                 const int* __restrict__ labels,
                 const int* __restrict__ ids,
                 float2* __restrict__ pv) {
    __shared__ __align__(16) float negl[264];   // compacted r_neg + pen, padded
    __shared__ float wave_sums[4];
    __shared__ int wave_base[4];
    __shared__ int ncnt;

    const int b = blockIdx.x;
    const int t = threadIdx.x;
    const int lane = t & 63;
    const int wave = t >> 6;

    if (t == 0) ncnt = 0;

    // gather: thread t owns gathered column t (duplicates in ids are
    // duplicate threads — matches reference semantics exactly)
    const int c = ids[t];
    const float r = ranks[b * C_TOTAL + c];
    const int lab = labels[b * C_TOTAL + c];
    const bool isneg = (lab == 0);

    // wave-level compaction of negatives (order-independent sum)
    const unsigned long long m = __ballot(isneg);
    const int cnt_wave = __popcll(m);
    const int my_pos = __popcll(m & ((1ULL << lane) - 1ULL));

    __syncthreads();                      // ncnt == 0 visible
    if (lane == 0) wave_base[wave] = atomicAdd(&ncnt, cnt_wave);
    __syncthreads();

    const int N = ncnt;                   // negatives in this row
    const int Npad = (N + 7) & ~7;
    if (isneg) negl[wave_base[wave] + my_pos] = r + NEG_PEN;
    if (t >= N && t < Npad) negl[t] = -1e30f;   // pad -> relu==0
    __syncthreads();

    // positives pivot on own rank; negatives pivot=3e30 -> all terms 0
    const float rp = (lab == 1) ? r : 3e30f;

    float a0 = 0.f, a1 = 0.f, a2 = 0.f, a3 = 0.f;
    float a4 = 0.f, a5 = 0.f, a6 = 0.f, a7 = 0.f;
    const float4* n4 = (const float4*)negl;
    const int G = Npad >> 2;              // multiple of 2
    for (int g = 0; g < G; g += 2) {
        float4 x = n4[g];                 // LDS broadcast reads
        float4 y = n4[g + 1];
        a0 += fmaxf(x.x - rp, 0.0f);
        a1 += fmaxf(x.y - rp, 0.0f);
        a2 += fmaxf(x.z - rp, 0.0f);
        a3 += fmaxf(x.w - rp, 0.0f);
        a4 += fmaxf(y.x - rp, 0.0f);
        a5 += fmaxf(y.y - rp, 0.0f);
        a6 += fmaxf(y.z - rp, 0.0f);
        a7 += fmaxf(y.w - rp, 0.0f);
    }
    float acc = ((a0 + a1) + (a2 + a3)) + ((a4 + a5) + (a6 + a7));

    // wave reduction
#pragma unroll
    for (int off = 32; off > 0; off >>= 1) {
        acc += __shfl_down(acc, off, 64);
    }
    if (lane == 0) wave_sums[wave] = acc;
    __syncthreads();

    if (t == 0) {
        float s = (wave_sums[0] + wave_sums[1]) + (wave_sums[2] + wave_sums[3]);
        pv[b] = make_float2(s, (N < C_LOADED) ? 1.0f : 0.0f);
    }
}

__global__ void __launch_bounds__(1024)
finalize_kernel(const float4* __restrict__ pv4, float* __restrict__ out) {
    __shared__ float ws_s[16], ws_v[16];
    const int t = threadIdx.x;
    const int lane = t & 63;
    const int wave = t >> 6;

    const float4 v = pv4[t];              // two float2 entries per thread
    float s = v.x + v.z;
    float nv = v.y + v.w;

#pragma unroll
    for (int off = 32; off > 0; off >>= 1) {
        s  += __shfl_down(s, off, 64);
        nv += __shfl_down(nv, off, 64);
    }
    if (lane == 0) { ws_s[wave] = s; ws_v[wave] = nv; }
    __syncthreads();

    if (t == 0) {
        float ts = 0.f, tv = 0.f;
#pragma unroll
        for (int w = 0; w < 16; ++w) { ts += ws_s[w]; tv += ws_v[w]; }
        out[0] = ts / tv;
    }
}

extern "C" void kernel_launch(void* const* d_in, const int* in_sizes, int n_in,
                              void* d_out, int out_size, void* d_ws, size_t ws_size,
                              hipStream_t stream) {
    const float* ranks  = (const float*)d_in[0];
    const int*   labels = (const int*)d_in[1];
    const int*   ids    = (const int*)d_in[2];
    float* out = (float*)d_out;

    float2* pv = (float2*)d_ws;

    rank_loss_kernel<<<B_ROWS, C_LOADED, 0, stream>>>(ranks, labels, ids, pv);
    finalize_kernel<<<1, 1024, 0, stream>>>((const float4*)pv, out);
}